// Round 1
// baseline (368.005 us; speedup 1.0000x reference)
//
#include <hip/hip_runtime.h>
#include <cstdint>

#define K_DIM 4096
#define BM 128
#define BN 128
#define BK 32

typedef __bf16 bf16x8 __attribute__((ext_vector_type(8)));
typedef float f32x4 __attribute__((ext_vector_type(4)));

// round-to-nearest-even float -> bf16 bits (finite values)
__device__ inline unsigned short f2bf(float f) {
    union { float f; unsigned int u; } v; v.f = f;
    unsigned int u = v.u;
    unsigned int r = (u + 0x7FFFu + ((u >> 16) & 1u)) >> 16;
    return (unsigned short)r;
}

__device__ inline void gload16(const void* g, void* l) {
    __builtin_amdgcn_global_load_lds(
        (const __attribute__((address_space(1))) unsigned int*)g,
        (__attribute__((address_space(3))) unsigned int*)l,
        16, 0, 0);
}

// out[e] = bf16(q[e] * s[e/16]); one thread handles 8 consecutive elements
__global__ __launch_bounds__(256) void dequant_kernel(
        const float* __restrict__ q, const float* __restrict__ s,
        unsigned short* __restrict__ out, long total8) {
    long i = (long)blockIdx.x * blockDim.x + threadIdx.x;
    if (i >= total8) return;
    long e = i * 8;
    float sc = s[e >> 4];
    float4 v0 = *(const float4*)(q + e);
    float4 v1 = *(const float4*)(q + e + 4);
    union { unsigned short h[8]; uint4 u; } o;
    o.h[0] = f2bf(v0.x * sc); o.h[1] = f2bf(v0.y * sc);
    o.h[2] = f2bf(v0.z * sc); o.h[3] = f2bf(v0.w * sc);
    o.h[4] = f2bf(v1.x * sc); o.h[5] = f2bf(v1.y * sc);
    o.h[6] = f2bf(v1.z * sc); o.h[7] = f2bf(v1.w * sc);
    *(uint4*)(out + e) = o.u;
}

// C[m][n] = sum_k A[m][k]*B[n][k] (both bf16, B^T layout), epilogue *gs + bias
template <bool FUSED>
__global__ __launch_bounds__(256) void gemm_kernel(
        const unsigned short* __restrict__ A,   // [M][K] bf16 (PRE path)
        const unsigned short* __restrict__ B,   // [N][K] bf16 (PRE path)
        const float* __restrict__ qx, const float* __restrict__ sx,
        const float* __restrict__ qw, const float* __restrict__ sw,
        const float* __restrict__ sg1, const float* __restrict__ sg2,
        const float* __restrict__ bias,
        float* __restrict__ out, int M, int N) {
    __shared__ __align__(16) unsigned short As[BM * BK];
    __shared__ __align__(16) unsigned short Bs[BN * BK];

    const int tid  = threadIdx.x;
    const int lane = tid & 63;
    const int wid  = tid >> 6;
    const int tile_n = blockIdx.x * BN;
    const int tile_m = blockIdx.y * BM;
    const int wm = wid >> 1, wn = wid & 1;   // wave's 64x64 sub-tile

    f32x4 acc[16];
#pragma unroll
    for (int i = 0; i < 16; ++i) acc[i] = (f32x4){0.f, 0.f, 0.f, 0.f};

    const int l15 = lane & 15;
    const int lk  = (lane >> 4) * 8;

    for (int kt = 0; kt < K_DIM / BK; ++kt) {
        if constexpr (!FUSED) {
            // global -> LDS direct, 16B/lane; wave w covers 16-row chunks {w, w+4}
            const int r  = lane >> 2;
            const int kc = (lane & 3) * 8;
            const long gk = (long)kt * BK + kc;
            gload16(A + (long)(tile_m + wid * 16 + r) * K_DIM + gk,
                    (char*)As + wid * 1024);
            gload16(A + (long)(tile_m + 64 + wid * 16 + r) * K_DIM + gk,
                    (char*)As + 4096 + wid * 1024);
            gload16(B + (long)(tile_n + wid * 16 + r) * K_DIM + gk,
                    (char*)Bs + wid * 1024);
            gload16(B + (long)(tile_n + 64 + wid * 16 + r) * K_DIM + gk,
                    (char*)Bs + 4096 + wid * 1024);
        } else {
            // fused dequant staging: 8 f32 -> 8 bf16 per chunk, 2 chunks/thread
#pragma unroll
            for (int cc = 0; cc < 2; ++cc) {
                const int c   = tid + cc * 256;        // 0..511
                const int row = c >> 2;
                const int col = (c & 3) * 8;
                const int gk  = kt * BK + col;
                {
                    const float* qp = qx + (long)(tile_m + row) * K_DIM + gk;
                    float s = sx[(long)(tile_m + row) * (K_DIM / 16) + (gk >> 4)];
                    float4 a0 = *(const float4*)qp;
                    float4 a1 = *(const float4*)(qp + 4);
                    union { unsigned short h[8]; uint4 u; } o;
                    o.h[0] = f2bf(a0.x * s); o.h[1] = f2bf(a0.y * s);
                    o.h[2] = f2bf(a0.z * s); o.h[3] = f2bf(a0.w * s);
                    o.h[4] = f2bf(a1.x * s); o.h[5] = f2bf(a1.y * s);
                    o.h[6] = f2bf(a1.z * s); o.h[7] = f2bf(a1.w * s);
                    *(uint4*)&As[row * BK + col] = o.u;
                }
                {
                    const float* qp = qw + (long)(tile_n + row) * K_DIM + gk;
                    float s = sw[(long)(tile_n + row) * (K_DIM / 16) + (gk >> 4)];
                    float4 a0 = *(const float4*)qp;
                    float4 a1 = *(const float4*)(qp + 4);
                    union { unsigned short h[8]; uint4 u; } o;
                    o.h[0] = f2bf(a0.x * s); o.h[1] = f2bf(a0.y * s);
                    o.h[2] = f2bf(a0.z * s); o.h[3] = f2bf(a0.w * s);
                    o.h[4] = f2bf(a1.x * s); o.h[5] = f2bf(a1.y * s);
                    o.h[6] = f2bf(a1.z * s); o.h[7] = f2bf(a1.w * s);
                    *(uint4*)&Bs[row * BK + col] = o.u;
                }
            }
        }
        __syncthreads();   // drains vmcnt/lgkmcnt before barrier

        const unsigned short* pa = As + (wm * 64 + l15) * BK + lk;
        const unsigned short* pb = Bs + (wn * 64 + l15) * BK + lk;
        bf16x8 a[4], b[4];
#pragma unroll
        for (int i = 0; i < 4; ++i) {
            a[i] = *(const bf16x8*)(pa + i * 16 * BK);
            b[i] = *(const bf16x8*)(pb + i * 16 * BK);
        }
#pragma unroll
        for (int mi = 0; mi < 4; ++mi)
#pragma unroll
            for (int ni = 0; ni < 4; ++ni)
                acc[mi * 4 + ni] = __builtin_amdgcn_mfma_f32_16x16x32_bf16(
                    a[mi], b[ni], acc[mi * 4 + ni], 0, 0, 0);

        __syncthreads();   // protect LDS before next stage
    }

    // epilogue: C/D layout col=lane&15, row=(lane>>4)*4+reg
    const float gs = sg1[0] * sg2[0];
    const int row0 = tile_m + wm * 64 + (lane >> 4) * 4;
    const int col0 = tile_n + wn * 64 + l15;
#pragma unroll
    for (int mi = 0; mi < 4; ++mi) {
#pragma unroll
        for (int ni = 0; ni < 4; ++ni) {
            const int col = col0 + ni * 16;
            const float bv = bias[col];
#pragma unroll
            for (int j = 0; j < 4; ++j) {
                const int row = row0 + mi * 16 + j;
                out[(long)row * N + col] = acc[mi * 4 + ni][j] * gs + bv;
            }
        }
    }
}

extern "C" void kernel_launch(void* const* d_in, const int* in_sizes, int n_in,
                              void* d_out, int out_size, void* d_ws, size_t ws_size,
                              hipStream_t stream) {
    const float* qx   = (const float*)d_in[0];
    const float* sx   = (const float*)d_in[1];
    const float* sc   = (const float*)d_in[2];
    const float* qw   = (const float*)d_in[3];
    const float* sw   = (const float*)d_in[4];
    const float* swg  = (const float*)d_in[5];
    const float* bias = (const float*)d_in[6];
    float* out = (float*)d_out;

    const int M = in_sizes[0] / K_DIM;   // 8192
    const int N = in_sizes[3] / K_DIM;   // 4096

    const size_t needA = (size_t)M * K_DIM * sizeof(unsigned short);
    const size_t needB = (size_t)N * K_DIM * sizeof(unsigned short);

    dim3 grid(N / BN, M / BM), block(256);

    if (ws_size >= needA + needB) {
        unsigned short* xd = (unsigned short*)d_ws;
        unsigned short* wd = (unsigned short*)((char*)d_ws + needA);
        long t8x = (long)M * K_DIM / 8;
        long t8w = (long)N * K_DIM / 8;
        dequant_kernel<<<(int)((t8x + 255) / 256), 256, 0, stream>>>(qx, sx, xd, t8x);
        dequant_kernel<<<(int)((t8w + 255) / 256), 256, 0, stream>>>(qw, sw, wd, t8w);
        gemm_kernel<false><<<grid, block, 0, stream>>>(
            xd, wd, nullptr, nullptr, nullptr, nullptr, sc, swg, bias, out, M, N);
    } else {
        gemm_kernel<true><<<grid, block, 0, stream>>>(
            nullptr, nullptr, qx, sx, qw, sw, sc, swg, bias, out, M, N);
    }
}

// Round 2
// 289.547 us; speedup vs baseline: 1.2710x; 1.2710x over previous
//
#include <hip/hip_runtime.h>
#include <cstdint>

#define K_DIM 4096
#define ROWB 13              // log2(K_DIM*2) byte row stride
#define NU   (K_DIM / 32)    // 128 K-units of 32 cols

typedef __bf16 bf16x8 __attribute__((ext_vector_type(8)));
typedef float f32x4 __attribute__((ext_vector_type(4)));

// round-to-nearest-even float -> bf16 bits
__device__ inline unsigned short f2bf(float f) {
    union { float f; unsigned int u; } v; v.f = f;
    unsigned int u = v.u;
    return (unsigned short)((u + 0x7FFFu + ((u >> 16) & 1u)) >> 16);
}

__device__ inline void gload16(const void* g, void* l) {
    __builtin_amdgcn_global_load_lds(
        (const __attribute__((address_space(1))) unsigned int*)g,
        (__attribute__((address_space(3))) unsigned int*)l,
        16, 0, 0);
}

// fused dequant of both operands: out[e] = bf16(q[e] * s[e/16])
__global__ __launch_bounds__(256) void dequant2_kernel(
        const float* __restrict__ qx, const float* __restrict__ sx,
        unsigned short* __restrict__ xd, long t8x,
        const float* __restrict__ qw, const float* __restrict__ sw,
        unsigned short* __restrict__ wd, long t8w) {
    long i = (long)blockIdx.x * blockDim.x + threadIdx.x;
    if (i >= t8x + t8w) return;
    const float* q; const float* s; unsigned short* o;
    if (i < t8x) { q = qx; s = sx; o = xd; }
    else         { q = qw; s = sw; o = wd; i -= t8x; }
    long e = i * 8;
    float sc = s[e >> 4];
    float4 v0 = *(const float4*)(q + e);
    float4 v1 = *(const float4*)(q + e + 4);
    union { unsigned short h[8]; uint4 u; } ov;
    ov.h[0] = f2bf(v0.x * sc); ov.h[1] = f2bf(v0.y * sc);
    ov.h[2] = f2bf(v0.z * sc); ov.h[3] = f2bf(v0.w * sc);
    ov.h[4] = f2bf(v1.x * sc); ov.h[5] = f2bf(v1.y * sc);
    ov.h[6] = f2bf(v1.z * sc); ov.h[7] = f2bf(v1.w * sc);
    *(uint4*)(o + e) = ov.u;
}

// ---------------- 256x256 deep-pipelined bf16 GEMM ----------------
// C[m][n] = sum_k A[m][k]*B[n][k], epilogue *gs + bias.
// 8 waves (2M x 4N), per-wave 128x64 out. K processed in 32-wide units.
// 4 LDS slots (A 16KB + B 16KB each) = 128 KiB, 3-deep prefetch,
// counted vmcnt(8) at unit boundaries (never drains the load queue).
// LDS swizzle: 16B chunk c of row r stored at chunk c ^ ((r>>1)&3)
// (inverse applied to the per-lane GLOBAL address; LDS dest stays linear).

__device__ __forceinline__ const bf16x8* fragp(const char* base, int r, int cb) {
    return (const bf16x8*)(base + r * 64 + (cb ^ (((r >> 1) & 3) << 4)));
}

__device__ __forceinline__ void stage_group(const char* srcbase, int row0,
                                            int kb, int scb, char* ldsbase,
                                            int g, int lane) {
    // group g covers rows 16g..16g+15 of the tile; lane l -> row 16g+(l>>2),
    // source 16B chunk (l&3)^((l>>3)&3) so the linear LDS write lands swizzled
    const char* src = srcbase +
        ((size_t)(row0 + 16 * g + (lane >> 2)) << ROWB) + kb + scb;
    gload16(src, ldsbase + g * 1024);
}

__global__ __launch_bounds__(512, 2) void gemm256_kernel(
        const unsigned short* __restrict__ A,   // [M][K] bf16
        const unsigned short* __restrict__ B,   // [N][K] bf16
        const float* __restrict__ sg1, const float* __restrict__ sg2,
        const float* __restrict__ bias,
        float* __restrict__ out, int M, int N) {
    __shared__ __align__(16) char lds[131072];   // 4 slots x 32 KB

    const int tid  = threadIdx.x;
    const int lane = tid & 63;
    const int wid  = tid >> 6;       // 0..7
    const int wm   = wid >> 2;       // 0..1
    const int wn   = wid & 3;        // 0..3
    const int l15  = lane & 15;
    const int cb   = (lane >> 4) << 4;                          // frag chunk byte
    const int scb  = (((lane & 3) ^ ((lane >> 3) & 3))) << 4;   // staging src chunk

    // XCD-aware bijective block swizzle (nwg % 8 == 0)
    const int nbn = N >> 8;
    const int nwg = (M >> 8) * nbn;
    const int cpx = nwg >> 3;
    const int bid = blockIdx.x;
    const int swz = (bid & 7) * cpx + (bid >> 3);
    const int tile_m = (swz / nbn) << 8;
    const int tile_n = (swz % nbn) << 8;

    const char* Abase = (const char*)A;
    const char* Bbase = (const char*)B;

    f32x4 acc[8][4];
#pragma unroll
    for (int mb = 0; mb < 8; ++mb)
#pragma unroll
        for (int nb = 0; nb < 4; ++nb) acc[mb][nb] = (f32x4){0.f, 0.f, 0.f, 0.f};

    // prologue: stage units 0,1,2 into slots 0,1,2 (4 loads/thread each)
    for (int pu = 0; pu < 3; ++pu) {
        char* Sb = lds + (pu << 15);
        const int kb = pu << 6;
        stage_group(Abase, tile_m, kb, scb, Sb,        2 * wid,     lane);
        stage_group(Abase, tile_m, kb, scb, Sb,        2 * wid + 1, lane);
        stage_group(Bbase, tile_n, kb, scb, Sb + 16384, 2 * wid,     lane);
        stage_group(Bbase, tile_n, kb, scb, Sb + 16384, 2 * wid + 1, lane);
    }
    asm volatile("s_waitcnt vmcnt(8)" ::: "memory");
    __builtin_amdgcn_s_barrier();

    for (int u = 0; u < NU; ++u) {
        const char* Ab = lds + ((u & 3) << 15);
        const char* Bb = Ab + 16384;
        char* Sb = lds + (((u + 3) & 3) << 15);
        const int us  = (u + 3 < NU) ? (u + 3) : (NU - 1);  // tail: redundant restage
        const int skb = us << 6;

        // ---- phase A: B-frags + A-frags(0..3) || stage next A-half ----
        bf16x8 bfr[4], a0[4], a1[4];
#pragma unroll
        for (int nb = 0; nb < 4; ++nb)
            bfr[nb] = *fragp(Bb, wn * 64 + nb * 16 + l15, cb);
#pragma unroll
        for (int mb = 0; mb < 4; ++mb)
            a0[mb] = *fragp(Ab, wm * 128 + mb * 16 + l15, cb);
        stage_group(Abase, tile_m, skb, scb, Sb, 2 * wid,     lane);
        stage_group(Abase, tile_m, skb, scb, Sb, 2 * wid + 1, lane);
        __builtin_amdgcn_s_barrier();
        __builtin_amdgcn_s_setprio(1);
#pragma unroll
        for (int mb = 0; mb < 4; ++mb)
#pragma unroll
            for (int nb = 0; nb < 4; ++nb)
                acc[mb][nb] = __builtin_amdgcn_mfma_f32_16x16x32_bf16(
                    a0[mb], bfr[nb], acc[mb][nb], 0, 0, 0);
        __builtin_amdgcn_s_setprio(0);

        // ---- phase B: A-frags(4..7) || stage next B-half ----
#pragma unroll
        for (int mb = 0; mb < 4; ++mb)
            a1[mb] = *fragp(Ab, wm * 128 + (mb + 4) * 16 + l15, cb);
        stage_group(Bbase, tile_n, skb, scb, Sb + 16384, 2 * wid,     lane);
        stage_group(Bbase, tile_n, skb, scb, Sb + 16384, 2 * wid + 1, lane);
        __builtin_amdgcn_s_barrier();
        __builtin_amdgcn_s_setprio(1);
#pragma unroll
        for (int mb = 0; mb < 4; ++mb)
#pragma unroll
            for (int nb = 0; nb < 4; ++nb)
                acc[mb + 4][nb] = __builtin_amdgcn_mfma_f32_16x16x32_bf16(
                    a1[mb], bfr[nb], acc[mb + 4][nb], 0, 0, 0);
        __builtin_amdgcn_s_setprio(0);

        // unit boundary: unit u+1 resident once only the newest 8 loads remain
        asm volatile("s_waitcnt vmcnt(8)" ::: "memory");
        __builtin_amdgcn_s_barrier();
    }

    // epilogue: C/D layout col=lane&15, row=(lane>>4)*4+j
    const float gs = sg1[0] * sg2[0];
    const int row0 = tile_m + wm * 128 + ((lane >> 4) << 2);
    const int col0 = tile_n + wn * 64 + l15;
    float bv[4];
#pragma unroll
    for (int nb = 0; nb < 4; ++nb) bv[nb] = bias[col0 + nb * 16];
#pragma unroll
    for (int mb = 0; mb < 8; ++mb)
#pragma unroll
        for (int nb = 0; nb < 4; ++nb) {
            const int col = col0 + nb * 16;
#pragma unroll
            for (int j = 0; j < 4; ++j)
                out[(size_t)(row0 + mb * 16 + j) * N + col] =
                    acc[mb][nb][j] * gs + bv[nb];
        }
}

// ---------------- fallback: fused-dequant 128^2 GEMM (ws too small) ----------------
__global__ __launch_bounds__(256) void gemm_fused_kernel(
        const float* __restrict__ qx, const float* __restrict__ sx,
        const float* __restrict__ qw, const float* __restrict__ sw,
        const float* __restrict__ sg1, const float* __restrict__ sg2,
        const float* __restrict__ bias,
        float* __restrict__ out, int M, int N) {
    __shared__ __align__(16) unsigned short As[128 * 32];
    __shared__ __align__(16) unsigned short Bs[128 * 32];
    const int tid  = threadIdx.x;
    const int lane = tid & 63;
    const int wid  = tid >> 6;
    const int tile_n = blockIdx.x * 128;
    const int tile_m = blockIdx.y * 128;
    const int wm = wid >> 1, wn = wid & 1;
    f32x4 acc[16];
#pragma unroll
    for (int i = 0; i < 16; ++i) acc[i] = (f32x4){0.f, 0.f, 0.f, 0.f};
    const int l15 = lane & 15;
    const int lk  = (lane >> 4) * 8;
    for (int kt = 0; kt < K_DIM / 32; ++kt) {
#pragma unroll
        for (int cc = 0; cc < 2; ++cc) {
            const int c   = tid + cc * 256;
            const int row = c >> 2;
            const int col = (c & 3) * 8;
            const int gk  = kt * 32 + col;
            {
                const float* qp = qx + (long)(tile_m + row) * K_DIM + gk;
                float s = sx[(long)(tile_m + row) * (K_DIM / 16) + (gk >> 4)];
                float4 a0 = *(const float4*)qp;
                float4 a1 = *(const float4*)(qp + 4);
                union { unsigned short h[8]; uint4 u; } o;
                o.h[0] = f2bf(a0.x * s); o.h[1] = f2bf(a0.y * s);
                o.h[2] = f2bf(a0.z * s); o.h[3] = f2bf(a0.w * s);
                o.h[4] = f2bf(a1.x * s); o.h[5] = f2bf(a1.y * s);
                o.h[6] = f2bf(a1.z * s); o.h[7] = f2bf(a1.w * s);
                *(uint4*)&As[row * 32 + col] = o.u;
            }
            {
                const float* qp = qw + (long)(tile_n + row) * K_DIM + gk;
                float s = sw[(long)(tile_n + row) * (K_DIM / 16) + (gk >> 4)];
                float4 a0 = *(const float4*)qp;
                float4 a1 = *(const float4*)(qp + 4);
                union { unsigned short h[8]; uint4 u; } o;
                o.h[0] = f2bf(a0.x * s); o.h[1] = f2bf(a0.y * s);
                o.h[2] = f2bf(a0.z * s); o.h[3] = f2bf(a0.w * s);
                o.h[4] = f2bf(a1.x * s); o.h[5] = f2bf(a1.y * s);
                o.h[6] = f2bf(a1.z * s); o.h[7] = f2bf(a1.w * s);
                *(uint4*)&Bs[row * 32 + col] = o.u;
            }
        }
        __syncthreads();
        const unsigned short* pa = As + (wm * 64 + l15) * 32 + lk;
        const unsigned short* pb = Bs + (wn * 64 + l15) * 32 + lk;
        bf16x8 a[4], b[4];
#pragma unroll
        for (int i = 0; i < 4; ++i) {
            a[i] = *(const bf16x8*)(pa + i * 16 * 32);
            b[i] = *(const bf16x8*)(pb + i * 16 * 32);
        }
#pragma unroll
        for (int mi = 0; mi < 4; ++mi)
#pragma unroll
            for (int ni = 0; ni < 4; ++ni)
                acc[mi * 4 + ni] = __builtin_amdgcn_mfma_f32_16x16x32_bf16(
                    a[mi], b[ni], acc[mi * 4 + ni], 0, 0, 0);
        __syncthreads();
    }
    const float gs = sg1[0] * sg2[0];
    const int row0 = tile_m + wm * 64 + (lane >> 4) * 4;
    const int col0 = tile_n + wn * 64 + l15;
#pragma unroll
    for (int mi = 0; mi < 4; ++mi)
#pragma unroll
        for (int ni = 0; ni < 4; ++ni) {
            const int col = col0 + ni * 16;
            const float bv = bias[col];
#pragma unroll
            for (int j = 0; j < 4; ++j)
                out[(long)(row0 + mi * 16 + j) * N + col] =
                    acc[mi * 4 + ni][j] * gs + bv;
        }
}

extern "C" void kernel_launch(void* const* d_in, const int* in_sizes, int n_in,
                              void* d_out, int out_size, void* d_ws, size_t ws_size,
                              hipStream_t stream) {
    const float* qx   = (const float*)d_in[0];
    const float* sx   = (const float*)d_in[1];
    const float* sc   = (const float*)d_in[2];
    const float* qw   = (const float*)d_in[3];
    const float* sw   = (const float*)d_in[4];
    const float* swg  = (const float*)d_in[5];
    const float* bias = (const float*)d_in[6];
    float* out = (float*)d_out;

    const int M = in_sizes[0] / K_DIM;   // 8192
    const int N = in_sizes[3] / K_DIM;   // 4096

    const size_t needA = (size_t)M * K_DIM * sizeof(unsigned short);
    const size_t needB = (size_t)N * K_DIM * sizeof(unsigned short);

    if (ws_size >= needA + needB) {
        unsigned short* xd = (unsigned short*)d_ws;
        unsigned short* wd = (unsigned short*)((char*)d_ws + needA);
        long t8x = (long)M * K_DIM / 8;
        long t8w = (long)N * K_DIM / 8;
        long tot = t8x + t8w;
        dequant2_kernel<<<(int)((tot + 255) / 256), 256, 0, stream>>>(
            qx, sx, xd, t8x, qw, sw, wd, t8w);
        const int nwg = (M / 256) * (N / 256);
        gemm256_kernel<<<nwg, 512, 0, stream>>>(xd, wd, sc, swg, bias, out, M, N);
    } else {
        dim3 grid(N / 128, M / 128);
        gemm_fused_kernel<<<grid, 256, 0, stream>>>(
            qx, sx, qw, sw, sc, swg, bias, out, M, N);
    }
}

// Round 3
// 283.788 us; speedup vs baseline: 1.2968x; 1.0203x over previous
//
#include <hip/hip_runtime.h>
#include <cstdint>

#define K_DIM 4096
#define ROWB 13              // log2(K_DIM*2) byte row stride
#define NU   (K_DIM / 32)    // 128 K-units of 32 cols

typedef __bf16 bf16x8 __attribute__((ext_vector_type(8)));
typedef float f32x4 __attribute__((ext_vector_type(4)));

// round-to-nearest-even float -> bf16 bits
__device__ inline unsigned short f2bf(float f) {
    union { float f; unsigned int u; } v; v.f = f;
    unsigned int u = v.u;
    return (unsigned short)((u + 0x7FFFu + ((u >> 16) & 1u)) >> 16);
}

__device__ __forceinline__ void gload16(const void* g, void* l) {
    __builtin_amdgcn_global_load_lds(
        (const __attribute__((address_space(1))) unsigned int*)g,
        (__attribute__((address_space(3))) unsigned int*)l,
        16, 0, 0);
}

// fused dequant of both operands: out[e] = bf16(q[e] * s[e/16])
__global__ __launch_bounds__(256) void dequant2_kernel(
        const float* __restrict__ qx, const float* __restrict__ sx,
        unsigned short* __restrict__ xd, long t8x,
        const float* __restrict__ qw, const float* __restrict__ sw,
        unsigned short* __restrict__ wd, long t8w) {
    long i = (long)blockIdx.x * blockDim.x + threadIdx.x;
    if (i >= t8x + t8w) return;
    const float* q; const float* s; unsigned short* o;
    if (i < t8x) { q = qx; s = sx; o = xd; }
    else         { q = qw; s = sw; o = wd; i -= t8x; }
    long e = i * 8;
    float sc = s[e >> 4];
    float4 v0 = *(const float4*)(q + e);
    float4 v1 = *(const float4*)(q + e + 4);
    union { unsigned short h[8]; uint4 u; } ov;
    ov.h[0] = f2bf(v0.x * sc); ov.h[1] = f2bf(v0.y * sc);
    ov.h[2] = f2bf(v0.z * sc); ov.h[3] = f2bf(v0.w * sc);
    ov.h[4] = f2bf(v1.x * sc); ov.h[5] = f2bf(v1.y * sc);
    ov.h[6] = f2bf(v1.z * sc); ov.h[7] = f2bf(v1.w * sc);
    *(uint4*)(o + e) = ov.u;
}

// ---------------- 256x256 deep-pipelined bf16 GEMM ----------------
// 8 waves (2M x 4N), per-wave 128x64 out. K in 32-wide units.
// 4 LDS slots (A 16KB + B 16KB) = 128 KiB, 3-deep prefetch, vmcnt(8)
// at unit boundaries (never drains). LDS swizzle: 16B chunk c of row r
// at chunk c ^ ((r>>1)&3); inverse applied to per-lane GLOBAL address.
// Round-3: hoisted global cursors + LDS offsets, unit loop unrolled x4
// so all slot bases are compile-time.

__global__ __launch_bounds__(512, 2) void gemm256_kernel(
        const unsigned short* __restrict__ A,   // [M][K] bf16
        const unsigned short* __restrict__ B,   // [N][K] bf16
        const float* __restrict__ sg1, const float* __restrict__ sg2,
        const float* __restrict__ bias,
        float* __restrict__ out, int M, int N) {
    __shared__ __align__(16) char lds[131072];   // 4 slots x 32 KB

    const int tid  = threadIdx.x;
    const int lane = tid & 63;
    const int wid  = tid >> 6;       // 0..7
    const int wm   = wid >> 2;       // 0..1
    const int wn   = wid & 3;        // 0..3
    const int l15  = lane & 15;
    const int cb   = (lane >> 4) << 4;                        // frag chunk byte
    const int scb  = ((lane & 3) ^ ((lane >> 3) & 3)) << 4;   // staging src chunk

    // XCD-aware bijective block swizzle (nwg % 8 == 0)
    const int nbn = N >> 8;
    const int nwg = (M >> 8) * nbn;
    const int cpx = nwg >> 3;
    const int bid = blockIdx.x;
    const int swz = (bid & 7) * cpx + (bid >> 3);
    const int tile_m = (swz / nbn) << 8;
    const int tile_n = (swz % nbn) << 8;

    // per-thread global staging cursors (unit-0 addresses); +u*64 per unit
    const int grow = lane >> 2;      // row within 16-row group
    const char* gA0 = (const char*)A +
        ((size_t)(tile_m + 32 * wid + grow) << ROWB) + scb;
    const char* gA1 = gA0 + ((size_t)16 << ROWB);
    const char* gB0 = (const char*)B +
        ((size_t)(tile_n + 32 * wid + grow) << ROWB) + scb;
    const char* gB1 = gB0 + ((size_t)16 << ROWB);
    // LDS staging dest offsets (wave-uniform), within 32KB slot
    const int dA0 = wid * 2048;             // A region [0,16K)
    const int dB0 = 16384 + wid * 2048;     // B region [16K,32K)

    // per-thread LDS fragment read offsets (swizzle XOR is invariant
    // across +16-row steps and across units)
    const int arow = wm * 128 + l15;
    const int aoff = arow * 64 + (cb ^ (((arow >> 1) & 3) << 4));  // +mb*1024
    const int brow = wn * 64 + l15;
    const int boff = 16384 + brow * 64 + (cb ^ (((brow >> 1) & 3) << 4));

    f32x4 acc[8][4];
#pragma unroll
    for (int mb = 0; mb < 8; ++mb)
#pragma unroll
        for (int nb = 0; nb < 4; ++nb) acc[mb][nb] = (f32x4){0.f, 0.f, 0.f, 0.f};

    // prologue: stage units 0,1,2 into slots 0,1,2
#pragma unroll
    for (int pu = 0; pu < 3; ++pu) {
        char* Sb = lds + (pu << 15);
        const int kb = pu << 6;
        gload16(gA0 + kb, Sb + dA0);
        gload16(gA1 + kb, Sb + dA0 + 1024);
        gload16(gB0 + kb, Sb + dB0);
        gload16(gB1 + kb, Sb + dB0 + 1024);
    }
    asm volatile("s_waitcnt vmcnt(8)" ::: "memory");
    __builtin_amdgcn_s_barrier();

    for (int ub = 0; ub < NU; ub += 4) {
#pragma unroll
        for (int uu = 0; uu < 4; ++uu) {
            const int u = ub + uu;
            const char* Ab = lds + (uu << 15);           // compile-time slot
            char* Sb = lds + (((uu + 3) & 3) << 15);     // compile-time slot
            const int skb = ((u + 3 < NU) ? (u + 3) : (NU - 1)) << 6;

            // ---- phase A: B-frags + A-frags(0..3) || stage next A-half ----
            bf16x8 bfr[4], afr[4];
#pragma unroll
            for (int nb = 0; nb < 4; ++nb)
                bfr[nb] = *(const bf16x8*)(Ab + boff + nb * 1024);
#pragma unroll
            for (int mb = 0; mb < 4; ++mb)
                afr[mb] = *(const bf16x8*)(Ab + aoff + mb * 1024);
            gload16(gA0 + skb, Sb + dA0);
            gload16(gA1 + skb, Sb + dA0 + 1024);
            __builtin_amdgcn_s_barrier();
            __builtin_amdgcn_s_setprio(1);
#pragma unroll
            for (int mb = 0; mb < 4; ++mb)
#pragma unroll
                for (int nb = 0; nb < 4; ++nb)
                    acc[mb][nb] = __builtin_amdgcn_mfma_f32_16x16x32_bf16(
                        afr[mb], bfr[nb], acc[mb][nb], 0, 0, 0);
            __builtin_amdgcn_s_setprio(0);

            // ---- phase B: A-frags(4..7) || stage next B-half ----
            bf16x8 afr2[4];
#pragma unroll
            for (int mb = 0; mb < 4; ++mb)
                afr2[mb] = *(const bf16x8*)(Ab + aoff + 4096 + mb * 1024);
            gload16(gB0 + skb, Sb + dB0);
            gload16(gB1 + skb, Sb + dB0 + 1024);
            __builtin_amdgcn_s_barrier();
            __builtin_amdgcn_s_setprio(1);
#pragma unroll
            for (int mb = 0; mb < 4; ++mb)
#pragma unroll
                for (int nb = 0; nb < 4; ++nb)
                    acc[mb + 4][nb] = __builtin_amdgcn_mfma_f32_16x16x32_bf16(
                        afr2[mb], bfr[nb], acc[mb + 4][nb], 0, 0, 0);
            __builtin_amdgcn_s_setprio(0);

            // unit boundary: next unit resident once only newest 8 remain
            asm volatile("s_waitcnt vmcnt(8)" ::: "memory");
            __builtin_amdgcn_s_barrier();
        }
    }

    // epilogue: C/D layout col=lane&15, row=(lane>>4)*4+j
    const float gs = sg1[0] * sg2[0];
    const int row0 = tile_m + wm * 128 + ((lane >> 4) << 2);
    const int col0 = tile_n + wn * 64 + l15;
    float bv[4];
#pragma unroll
    for (int nb = 0; nb < 4; ++nb) bv[nb] = bias[col0 + nb * 16];
#pragma unroll
    for (int mb = 0; mb < 8; ++mb)
#pragma unroll
        for (int nb = 0; nb < 4; ++nb) {
            const int col = col0 + nb * 16;
#pragma unroll
            for (int j = 0; j < 4; ++j)
                out[(size_t)(row0 + mb * 16 + j) * N + col] =
                    acc[mb][nb][j] * gs + bv[nb];
        }
}

// ---------------- fallback: fused-dequant 128^2 GEMM (ws too small) ----------------
__global__ __launch_bounds__(256) void gemm_fused_kernel(
        const float* __restrict__ qx, const float* __restrict__ sx,
        const float* __restrict__ qw, const float* __restrict__ sw,
        const float* __restrict__ sg1, const float* __restrict__ sg2,
        const float* __restrict__ bias,
        float* __restrict__ out, int M, int N) {
    __shared__ __align__(16) unsigned short As[128 * 32];
    __shared__ __align__(16) unsigned short Bs[128 * 32];
    const int tid  = threadIdx.x;
    const int lane = tid & 63;
    const int wid  = tid >> 6;
    const int tile_n = blockIdx.x * 128;
    const int tile_m = blockIdx.y * 128;
    const int wm = wid >> 1, wn = wid & 1;
    f32x4 acc[16];
#pragma unroll
    for (int i = 0; i < 16; ++i) acc[i] = (f32x4){0.f, 0.f, 0.f, 0.f};
    const int l15 = lane & 15;
    const int lk  = (lane >> 4) * 8;
    for (int kt = 0; kt < K_DIM / 32; ++kt) {
#pragma unroll
        for (int cc = 0; cc < 2; ++cc) {
            const int c   = tid + cc * 256;
            const int row = c >> 2;
            const int col = (c & 3) * 8;
            const int gk  = kt * 32 + col;
            {
                const float* qp = qx + (long)(tile_m + row) * K_DIM + gk;
                float s = sx[(long)(tile_m + row) * (K_DIM / 16) + (gk >> 4)];
                float4 a0 = *(const float4*)qp;
                float4 a1 = *(const float4*)(qp + 4);
                union { unsigned short h[8]; uint4 u; } o;
                o.h[0] = f2bf(a0.x * s); o.h[1] = f2bf(a0.y * s);
                o.h[2] = f2bf(a0.z * s); o.h[3] = f2bf(a0.w * s);
                o.h[4] = f2bf(a1.x * s); o.h[5] = f2bf(a1.y * s);
                o.h[6] = f2bf(a1.z * s); o.h[7] = f2bf(a1.w * s);
                *(uint4*)&As[row * 32 + col] = o.u;
            }
            {
                const float* qp = qw + (long)(tile_n + row) * K_DIM + gk;
                float s = sw[(long)(tile_n + row) * (K_DIM / 16) + (gk >> 4)];
                float4 a0 = *(const float4*)qp;
                float4 a1 = *(const float4*)(qp + 4);
                union { unsigned short h[8]; uint4 u; } o;
                o.h[0] = f2bf(a0.x * s); o.h[1] = f2bf(a0.y * s);
                o.h[2] = f2bf(a0.z * s); o.h[3] = f2bf(a0.w * s);
                o.h[4] = f2bf(a1.x * s); o.h[5] = f2bf(a1.y * s);
                o.h[6] = f2bf(a1.z * s); o.h[7] = f2bf(a1.w * s);
                *(uint4*)&Bs[row * 32 + col] = o.u;
            }
        }
        __syncthreads();
        const unsigned short* pa = As + (wm * 64 + l15) * 32 + lk;
        const unsigned short* pb = Bs + (wn * 64 + l15) * 32 + lk;
        bf16x8 a[4], b[4];
#pragma unroll
        for (int i = 0; i < 4; ++i) {
            a[i] = *(const bf16x8*)(pa + i * 16 * 32);
            b[i] = *(const bf16x8*)(pb + i * 16 * 32);
        }
#pragma unroll
        for (int mi = 0; mi < 4; ++mi)
#pragma unroll
            for (int ni = 0; ni < 4; ++ni)
                acc[mi * 4 + ni] = __builtin_amdgcn_mfma_f32_16x16x32_bf16(
                    a[mi], b[ni], acc[mi * 4 + ni], 0, 0, 0);
        __syncthreads();
    }
    const float gs = sg1[0] * sg2[0];
    const int row0 = tile_m + wm * 64 + (lane >> 4) * 4;
    const int col0 = tile_n + wn * 64 + l15;
#pragma unroll
    for (int mi = 0; mi < 4; ++mi)
#pragma unroll
        for (int ni = 0; ni < 4; ++ni) {
            const int col = col0 + ni * 16;
            const float bv = bias[col];
#pragma unroll
            for (int j = 0; j < 4; ++j)
                out[(long)(row0 + mi * 16 + j) * N + col] =
                    acc[mi * 4 + ni][j] * gs + bv;
        }
}

extern "C" void kernel_launch(void* const* d_in, const int* in_sizes, int n_in,
                              void* d_out, int out_size, void* d_ws, size_t ws_size,
                              hipStream_t stream) {
    const float* qx   = (const float*)d_in[0];
    const float* sx   = (const float*)d_in[1];
    const float* sc   = (const float*)d_in[2];
    const float* qw   = (const float*)d_in[3];
    const float* sw   = (const float*)d_in[4];
    const float* swg  = (const float*)d_in[5];
    const float* bias = (const float*)d_in[6];
    float* out = (float*)d_out;

    const int M = in_sizes[0] / K_DIM;   // 8192
    const int N = in_sizes[3] / K_DIM;   // 4096

    const size_t needA = (size_t)M * K_DIM * sizeof(unsigned short);
    const size_t needB = (size_t)N * K_DIM * sizeof(unsigned short);

    if (ws_size >= needA + needB) {
        unsigned short* xd = (unsigned short*)d_ws;
        unsigned short* wd = (unsigned short*)((char*)d_ws + needA);
        long t8x = (long)M * K_DIM / 8;
        long t8w = (long)N * K_DIM / 8;
        long tot = t8x + t8w;
        dequant2_kernel<<<(int)((tot + 255) / 256), 256, 0, stream>>>(
            qx, sx, xd, t8x, qw, sw, wd, t8w);
        const int nwg = (M / 256) * (N / 256);
        gemm256_kernel<<<nwg, 512, 0, stream>>>(xd, wd, sc, swg, bias, out, M, N);
    } else {
        dim3 grid(N / 128, M / 128);
        gemm_fused_kernel<<<grid, 256, 0, stream>>>(
            qx, sx, qw, sw, sc, swg, bias, out, M, N);
    }
}